// Round 5
// baseline (141.524 us; speedup 1.0000x reference)
//
#include <hip/hip_runtime.h>

#define B_  2
#define T_  2048
#define D_  512
#define H_  8
#define HD_ 64
#define WHALF_ 16
#define Mtot (B_*T_)
#define QKV_LD 1536

typedef __attribute__((ext_vector_type(8))) short short8;   // 8 bf16 in 4 VGPRs
typedef __attribute__((ext_vector_type(4))) float floatx4;  // MFMA accumulator

__device__ __forceinline__ unsigned short f2bf(float f) {
    unsigned u = __float_as_uint(f);
    u = (u + 0x7fffu + ((u >> 16) & 1u)) >> 16;   // RNE
    return (unsigned short)u;
}

#define ALD 40   // padded LDS row (80 B): 16B-aligned fragment reads, benign banks

// ---------------------------------------------------------------------------
// GEMM1: qkvb[4096,1536](bf16) = x[4096,512](f32) @ [Wq;Wk;Wv]^T + [bq;bk;bv]
// fp32 inputs cast to bf16 in-register during LDS staging (no cast kernels).
// Tile 128x64, BK=32, 768 blocks (3/CU). Each N-tile lies in one W matrix.
// ---------------------------------------------------------------------------
__global__ __launch_bounds__(256) void gemm_qkv(
    const float* __restrict__ x,
    const float* __restrict__ Wq, const float* __restrict__ Wk,
    const float* __restrict__ Wv,
    const float* __restrict__ bq, const float* __restrict__ bk,
    const float* __restrict__ bv,
    unsigned short* __restrict__ qkvb)
{
    __shared__ unsigned short As[128][ALD];
    __shared__ unsigned short Bs[64][ALD];

    const int t   = threadIdx.x;
    const int m0  = blockIdx.x * 128;
    const int n0g = blockIdx.y * 64;           // global col in [0,1536)
    const int mat = n0g >> 9;                  // 0:Q 1:K 2:V
    const int n0  = n0g & 511;                 // col within matrix
    const float* W    = (mat == 0) ? Wq : (mat == 1) ? Wk : Wv;
    const float* bias = (mat == 0) ? bq : (mat == 1) ? bk : bv;

    const int w = t >> 6, l = t & 63;
    const int quad = l >> 4, lo = l & 15;
    const int wm = w & 1, wn = w >> 1;

    floatx4 acc[4][2];
    #pragma unroll
    for (int i = 0; i < 4; ++i) { acc[i][0] = (floatx4)0.0f; acc[i][1] = (floatx4)0.0f; }

    for (int k0 = 0; k0 < 512; k0 += 32) {
        // A tile 128x32: 1024 float4 chunks, 4 per thread, cvt->bf16
        #pragma unroll
        for (int p = 0; p < 4; ++p) {
            int c = t + p * 256;
            int row = c >> 3, cg = (c & 7) * 4;
            float4 f = *(const float4*)(&x[(size_t)(m0 + row) * 512 + k0 + cg]);
            ushort4 o;
            o.x = f2bf(f.x); o.y = f2bf(f.y); o.z = f2bf(f.z); o.w = f2bf(f.w);
            *(ushort4*)(&As[row][cg]) = o;
        }
        // B tile 64x32: 512 float4 chunks, 2 per thread
        #pragma unroll
        for (int p = 0; p < 2; ++p) {
            int c = t + p * 256;
            int row = c >> 3, cg = (c & 7) * 4;
            float4 f = *(const float4*)(&W[(size_t)(n0 + row) * 512 + k0 + cg]);
            ushort4 o;
            o.x = f2bf(f.x); o.y = f2bf(f.y); o.z = f2bf(f.z); o.w = f2bf(f.w);
            *(ushort4*)(&Bs[row][cg]) = o;
        }
        __syncthreads();

        short8 b0 = *(const short8*)(&Bs[wn * 32 + lo][quad * 8]);
        short8 b1 = *(const short8*)(&Bs[wn * 32 + 16 + lo][quad * 8]);
        #pragma unroll
        for (int i = 0; i < 4; ++i) {
            short8 a = *(const short8*)(&As[wm * 64 + i * 16 + lo][quad * 8]);
            acc[i][0] = __builtin_amdgcn_mfma_f32_16x16x32_bf16(a, b0, acc[i][0], 0, 0, 0);
            acc[i][1] = __builtin_amdgcn_mfma_f32_16x16x32_bf16(a, b1, acc[i][1], 0, 0, 0);
        }
        __syncthreads();
    }

    // epilogue: C/D layout col=lane&15, row=quad*4+reg; bf16 out
    #pragma unroll
    for (int i = 0; i < 4; ++i) {
        int rbase = m0 + wm * 64 + i * 16 + quad * 4;
        #pragma unroll
        for (int j = 0; j < 2; ++j) {
            int colm = n0 + wn * 32 + j * 16 + lo;      // within-matrix col
            int colg = n0g + wn * 32 + j * 16 + lo;     // global col
            float bv = bias[colm];
            #pragma unroll
            for (int r = 0; r < 4; ++r)
                qkvb[(size_t)(rbase + r) * QKV_LD + colg] = f2bf(acc[i][j][r] + bv);
        }
    }
}

// ---------------------------------------------------------------------------
// GEMM2: out[4096,512](f32) = attb[4096,512](bf16) @ Wo^T(f32, inline cast)
//        + bo. Tile 64x64, BK=32, 512 blocks (2/CU). Wave w -> 16-row strip.
// ---------------------------------------------------------------------------
__global__ __launch_bounds__(256) void gemm_out(
    const unsigned short* __restrict__ attb, const float* __restrict__ Wo,
    const float* __restrict__ bo, float* __restrict__ out)
{
    __shared__ unsigned short As[64][ALD];
    __shared__ unsigned short Bs[64][ALD];

    const int t  = threadIdx.x;
    const int m0 = blockIdx.x * 64;
    const int n0 = blockIdx.y * 64;
    const int w = t >> 6, l = t & 63;
    const int quad = l >> 4, lo = l & 15;

    floatx4 acc[4];
    #pragma unroll
    for (int j = 0; j < 4; ++j) acc[j] = (floatx4)0.0f;

    const int arow = t >> 2, ako = (t & 3) * 8;   // A: 256 short8 chunks

    for (int k0 = 0; k0 < 512; k0 += 32) {
        *(short8*)(&As[arow][ako]) =
            *(const short8*)(&attb[(size_t)(m0 + arow) * 512 + k0 + ako]);
        #pragma unroll
        for (int p = 0; p < 2; ++p) {
            int c = t + p * 256;
            int row = c >> 3, cg = (c & 7) * 4;
            float4 f = *(const float4*)(&Wo[(size_t)(n0 + row) * 512 + k0 + cg]);
            ushort4 o;
            o.x = f2bf(f.x); o.y = f2bf(f.y); o.z = f2bf(f.z); o.w = f2bf(f.w);
            *(ushort4*)(&Bs[row][cg]) = o;
        }
        __syncthreads();

        short8 a = *(const short8*)(&As[w * 16 + lo][quad * 8]);
        #pragma unroll
        for (int j = 0; j < 4; ++j) {
            short8 b = *(const short8*)(&Bs[j * 16 + lo][quad * 8]);
            acc[j] = __builtin_amdgcn_mfma_f32_16x16x32_bf16(a, b, acc[j], 0, 0, 0);
        }
        __syncthreads();
    }

    #pragma unroll
    for (int j = 0; j < 4; ++j) {
        int col = n0 + j * 16 + lo;
        float bv = bo[col];
        #pragma unroll
        for (int r = 0; r < 4; ++r) {
            int row = m0 + w * 16 + quad * 4 + r;
            out[(size_t)row * 512 + col] = acc[j][r] + bv;
        }
    }
}

// ---------------------------------------------------------------------------
// MFMA local-window attention (unchanged — correct, ~6 us).
// ---------------------------------------------------------------------------
#define KR 96
#define QLD 72
#define VLDP 104

__global__ __launch_bounds__(256) void attn_mfma(
    const unsigned short* __restrict__ qkv, unsigned short* __restrict__ att)
{
    __shared__ unsigned short Qs[64][QLD];
    __shared__ unsigned short Ks[KR][QLD];
    __shared__ unsigned short Vt[64][VLDP];
    __shared__ unsigned short Pws[4][16][VLDP];

    const int q0 = blockIdx.x * 64;
    const int bh = blockIdx.y;
    const int b = bh >> 3, h = bh & 7;
    const int t = threadIdx.x;
    const int wq = t >> 6, l = t & 63;
    const int quad = l >> 4, lo = l & 15;

    const size_t baseQ = (size_t)(b * T_) * QKV_LD + h * HD_;

    for (int c = t; c < 512; c += 256) {
        int row = c >> 3, cg = c & 7;
        *(short8*)(&Qs[row][cg * 8]) =
            *(const short8*)(&qkv[baseQ + (size_t)(q0 + row) * QKV_LD + cg * 8]);
    }
    for (int c = t; c < 768; c += 256) {
        int row = c >> 3, cg = c & 7;
        int g = q0 - WHALF_ + row;
        short8 kv = (short8)(short)0;
        if (g >= 0 && g < T_)
            kv = *(const short8*)(&qkv[baseQ + 512 + (size_t)g * QKV_LD + cg * 8]);
        *(short8*)(&Ks[row][cg * 8]) = kv;
    }
    for (int c = t; c < 768; c += 256) {
        int row = c >> 3, cg = c & 7;
        int g = q0 - WHALF_ + row;
        short8 vv = (short8)(short)0;
        if (g >= 0 && g < T_)
            vv = *(const short8*)(&qkv[baseQ + 1024 + (size_t)g * QKV_LD + cg * 8]);
        #pragma unroll
        for (int j = 0; j < 8; ++j) Vt[cg * 8 + j][row] = vv[j];
    }
    __syncthreads();

    floatx4 S[6];
    #pragma unroll
    for (int kt = 0; kt < 6; ++kt) S[kt] = (floatx4)0.0f;
    short8 aq[2];
    #pragma unroll
    for (int ks = 0; ks < 2; ++ks)
        aq[ks] = *(const short8*)(&Qs[wq * 16 + lo][ks * 32 + quad * 8]);
    #pragma unroll
    for (int kt = 0; kt < 6; ++kt) {
        #pragma unroll
        for (int ks = 0; ks < 2; ++ks) {
            short8 bk8 = *(const short8*)(&Ks[kt * 16 + lo][ks * 32 + quad * 8]);
            S[kt] = __builtin_amdgcn_mfma_f32_16x16x32_bf16(aq[ks], bk8, S[kt], 0, 0, 0);
        }
    }

    float inv_r[4];
    #pragma unroll
    for (int r = 0; r < 4; ++r) {
        int qi = q0 + wq * 16 + quad * 4 + r;
        float mx = -1e30f;
        float sv[6]; bool vd[6];
        #pragma unroll
        for (int kt = 0; kt < 6; ++kt) {
            int j = q0 - WHALF_ + kt * 16 + lo;
            bool ok = (j >= qi - WHALF_) && (j < qi + WHALF_) && (j >= 0) && (j < T_);
            float s = S[kt][r] * 0.125f;
            sv[kt] = s; vd[kt] = ok;
            mx = (ok && s > mx) ? s : mx;
        }
        #pragma unroll
        for (int mm = 1; mm < 16; mm <<= 1) mx = fmaxf(mx, __shfl_xor(mx, mm, 16));
        float den = 0.f;
        #pragma unroll
        for (int kt = 0; kt < 6; ++kt) {
            float e = vd[kt] ? __expf(sv[kt] - mx) : 0.f;
            Pws[wq][quad * 4 + r][kt * 16 + lo] = f2bf(e);
            den += e;
        }
        #pragma unroll
        for (int mm = 1; mm < 16; mm <<= 1) den += __shfl_xor(den, mm, 16);
        inv_r[r] = 1.0f / den;
    }
    __syncthreads();

    floatx4 O[4];
    #pragma unroll
    for (int nt = 0; nt < 4; ++nt) O[nt] = (floatx4)0.0f;
    #pragma unroll
    for (int ks = 0; ks < 3; ++ks) {
        short8 ap = *(const short8*)(&Pws[wq][lo][ks * 32 + quad * 8]);
        #pragma unroll
        for (int nt = 0; nt < 4; ++nt) {
            short8 bv8 = *(const short8*)(&Vt[nt * 16 + lo][ks * 32 + quad * 8]);
            O[nt] = __builtin_amdgcn_mfma_f32_16x16x32_bf16(ap, bv8, O[nt], 0, 0, 0);
        }
    }

    #pragma unroll
    for (int r = 0; r < 4; ++r) {
        int qi = q0 + wq * 16 + quad * 4 + r;
        size_t rowb = (size_t)(b * T_ + qi) * D_ + h * HD_;
        #pragma unroll
        for (int nt = 0; nt < 4; ++nt)
            att[rowb + nt * 16 + lo] = f2bf(O[nt][r] * inv_r[r]);
    }
}

// ---------------------------------------------------------------------------
extern "C" void kernel_launch(void* const* d_in, const int* in_sizes, int n_in,
                              void* d_out, int out_size, void* d_ws, size_t ws_size,
                              hipStream_t stream) {
    const float* x  = (const float*)d_in[0];
    const float* Wq = (const float*)d_in[1];
    const float* bq = (const float*)d_in[2];
    const float* Wk = (const float*)d_in[3];
    const float* bk = (const float*)d_in[4];
    const float* Wv = (const float*)d_in[5];
    const float* bv = (const float*)d_in[6];
    const float* Wo = (const float*)d_in[7];
    const float* bo = (const float*)d_in[8];
    float* out = (float*)d_out;

    char* ws = (char*)d_ws;
    unsigned short* qkvb = (unsigned short*)(ws);              // 12.00 MB
    unsigned short* attb = (unsigned short*)(ws + 12582912);   //  4.00 MB

    // fused QKV projection with inline fp32->bf16 casts (no cast kernels)
    gemm_qkv<<<dim3(Mtot / 128, QKV_LD / 64), 256, 0, stream>>>(
        x, Wq, Wk, Wv, bq, bk, bv, qkvb);

    // local attention (bf16 in/out)
    attn_mfma<<<dim3(T_ / 64, B_ * H_), 256, 0, stream>>>(qkvb, attb);

    // output projection (inline Wo cast, fp32 out)
    gemm_out<<<dim3(Mtot / 64, D_ / 64), 256, 0, stream>>>(attb, Wo, bo, out);
}

// Round 6
// 108.574 us; speedup vs baseline: 1.3035x; 1.3035x over previous
//
#include <hip/hip_runtime.h>

#define B_  2
#define T_  2048
#define D_  512
#define H_  8
#define HD_ 64
#define WHALF_ 16
#define Mtot (B_*T_)
#define QKV_LD 1536

typedef __attribute__((ext_vector_type(8))) short short8;   // 8 bf16 in 4 VGPRs
typedef __attribute__((ext_vector_type(4))) float floatx4;  // MFMA accumulator

__device__ __forceinline__ unsigned short f2bf(float f) {
    unsigned u = __float_as_uint(f);
    u = (u + 0x7fffu + ((u >> 16) & 1u)) >> 16;   // RNE
    return (unsigned short)u;
}

__device__ __forceinline__ void glds16(const unsigned short* g, unsigned short* l) {
    // async global->LDS, 16 B/lane; LDS dest = wave-uniform base + lane*16
    __builtin_amdgcn_global_load_lds(
        (const __attribute__((address_space(1))) void*)g,
        (__attribute__((address_space(3))) void*)l, 16, 0, 0);
}

// ---------------------------------------------------------------------------
// One fused cast kernel: blocks 0..2047 cast x (fp32->bf16), 2048..3071 cast
// the 4 weight matrices into wqkv=[Wq;Wk;Wv] + wob, block 3072 packs bqkv.
// ---------------------------------------------------------------------------
__global__ __launch_bounds__(256) void cast_all(
    const float* __restrict__ x,
    const float* __restrict__ Wq, const float* __restrict__ Wk,
    const float* __restrict__ Wv, const float* __restrict__ Wo,
    const float* __restrict__ bq, const float* __restrict__ bk,
    const float* __restrict__ bv,
    unsigned short* __restrict__ xb,
    unsigned short* __restrict__ wqkv, unsigned short* __restrict__ wob,
    float* __restrict__ bqkv)
{
    if (blockIdx.x < 2048) {
        int i = blockIdx.x * 256 + threadIdx.x;
        float4 f = ((const float4*)x)[i];
        ushort4 o;
        o.x = f2bf(f.x); o.y = f2bf(f.y); o.z = f2bf(f.z); o.w = f2bf(f.w);
        ((ushort4*)xb)[i] = o;
    } else if (blockIdx.x < 3072) {
        int gid = (blockIdx.x - 2048) * 256 + threadIdx.x;
        int m   = gid >> 16;
        int idx = gid & 0xFFFF;
        const float* src = (m == 0) ? Wq : (m == 1) ? Wk : (m == 2) ? Wv : Wo;
        float4 f = ((const float4*)src)[idx];
        ushort4 o;
        o.x = f2bf(f.x); o.y = f2bf(f.y); o.z = f2bf(f.z); o.w = f2bf(f.w);
        if (m < 3) ((ushort4*)wqkv)[(m << 16) + idx] = o;
        else       ((ushort4*)wob)[idx] = o;
    } else {
        for (int i = threadIdx.x; i < 384; i += 256) {
            const float* src = (i < 128) ? bq : (i < 256) ? bk : bv;
            ((float4*)bqkv)[i] = ((const float4*)src)[i & 127];
        }
    }
}

// ---------------------------------------------------------------------------
// GEMM1: qkvb[4096,1536](bf16) = xb @ wqkv^T + bqkv.
// m97 structure: tile 128x64, BK=32, global_load_lds(16B) into UNPADDED LDS
// (layout forced by lane->base+lane*16). 768 blocks = 3/CU.
// Wave w: wm=w&1 (64-row half), wn=w>>1 (32-col half), 4x2 16x16x32 frags.
// ---------------------------------------------------------------------------
__global__ __launch_bounds__(256) void gemm_qkv(
    const unsigned short* __restrict__ A, const unsigned short* __restrict__ W,
    const float* __restrict__ bias, unsigned short* __restrict__ C)
{
    __shared__ unsigned short As[128 * 32];
    __shared__ unsigned short Bs[64 * 32];

    const int t  = threadIdx.x;
    const int m0 = blockIdx.x * 128;
    const int n0 = blockIdx.y * 64;
    const int w  = t >> 6, l = t & 63;
    const int quad = l >> 4, lo = l & 15;
    const int wm = w & 1, wn = w >> 1;

    const int lr = l >> 2, lk = (l & 3) * 8;   // chunk: 16 rows x 32 cols = 1 KB
    const unsigned short* Ag0 = A + (size_t)(m0 + (2 * w) * 16 + lr) * 512 + lk;
    const unsigned short* Ag1 = A + (size_t)(m0 + (2 * w + 1) * 16 + lr) * 512 + lk;
    const unsigned short* Bg  = W + (size_t)(n0 + w * 16 + lr) * 512 + lk;
    unsigned short* ldsA0 = &As[(2 * w) * 512];
    unsigned short* ldsA1 = &As[(2 * w + 1) * 512];
    unsigned short* ldsB  = &Bs[w * 512];

    floatx4 acc[4][2];
    #pragma unroll
    for (int i = 0; i < 4; ++i) { acc[i][0] = (floatx4)0.0f; acc[i][1] = (floatx4)0.0f; }

    for (int k0 = 0; k0 < 512; k0 += 32) {
        glds16(Ag0 + k0, ldsA0);
        glds16(Ag1 + k0, ldsA1);
        glds16(Bg + k0, ldsB);
        __syncthreads();

        short8 b0 = *(const short8*)(&Bs[(wn * 32 + lo) * 32 + quad * 8]);
        short8 b1 = *(const short8*)(&Bs[(wn * 32 + 16 + lo) * 32 + quad * 8]);
        #pragma unroll
        for (int i = 0; i < 4; ++i) {
            short8 a = *(const short8*)(&As[(wm * 64 + i * 16 + lo) * 32 + quad * 8]);
            acc[i][0] = __builtin_amdgcn_mfma_f32_16x16x32_bf16(a, b0, acc[i][0], 0, 0, 0);
            acc[i][1] = __builtin_amdgcn_mfma_f32_16x16x32_bf16(a, b1, acc[i][1], 0, 0, 0);
        }
        __syncthreads();
    }

    #pragma unroll
    for (int i = 0; i < 4; ++i) {
        int rbase = m0 + wm * 64 + i * 16 + quad * 4;
        #pragma unroll
        for (int j = 0; j < 2; ++j) {
            int col = n0 + wn * 32 + j * 16 + lo;
            float bv = bias[col];
            #pragma unroll
            for (int r = 0; r < 4; ++r)
                C[(size_t)(rbase + r) * QKV_LD + col] = f2bf(acc[i][j][r] + bv);
        }
    }
}

// ---------------------------------------------------------------------------
// GEMM2: out[4096,512](f32) = attb(bf16) @ wob^T + bo.
// Tile 64x64, BK=32, glds staging, 512 blocks = 2/CU.
// Wave w computes rows w*16..w*16+15 x all 64 cols (1 A-frag, 4 B-frags).
// ---------------------------------------------------------------------------
__global__ __launch_bounds__(256) void gemm_out(
    const unsigned short* __restrict__ attb, const unsigned short* __restrict__ wob,
    const float* __restrict__ bo, float* __restrict__ out)
{
    __shared__ unsigned short As[64 * 32];
    __shared__ unsigned short Bs[64 * 32];

    const int t  = threadIdx.x;
    const int m0 = blockIdx.x * 64;
    const int n0 = blockIdx.y * 64;
    const int w  = t >> 6, l = t & 63;
    const int quad = l >> 4, lo = l & 15;

    const int lr = l >> 2, lk = (l & 3) * 8;
    const unsigned short* Ag = attb + (size_t)(m0 + w * 16 + lr) * 512 + lk;
    const unsigned short* Bg = wob  + (size_t)(n0 + w * 16 + lr) * 512 + lk;
    unsigned short* ldsA = &As[w * 512];
    unsigned short* ldsB = &Bs[w * 512];

    floatx4 acc[4];
    #pragma unroll
    for (int j = 0; j < 4; ++j) acc[j] = (floatx4)0.0f;

    for (int k0 = 0; k0 < 512; k0 += 32) {
        glds16(Ag + k0, ldsA);
        glds16(Bg + k0, ldsB);
        __syncthreads();

        short8 a = *(const short8*)(&As[(w * 16 + lo) * 32 + quad * 8]);
        #pragma unroll
        for (int j = 0; j < 4; ++j) {
            short8 b = *(const short8*)(&Bs[(j * 16 + lo) * 32 + quad * 8]);
            acc[j] = __builtin_amdgcn_mfma_f32_16x16x32_bf16(a, b, acc[j], 0, 0, 0);
        }
        __syncthreads();
    }

    #pragma unroll
    for (int j = 0; j < 4; ++j) {
        int col = n0 + j * 16 + lo;
        float bv = bo[col];
        #pragma unroll
        for (int r = 0; r < 4; ++r) {
            int row = m0 + w * 16 + quad * 4 + r;
            out[(size_t)row * 512 + col] = acc[j][r] + bv;
        }
    }
}

// ---------------------------------------------------------------------------
// MFMA local-window attention (unchanged — correct).
// ---------------------------------------------------------------------------
#define KR 96
#define QLD 72
#define VLDP 104

__global__ __launch_bounds__(256) void attn_mfma(
    const unsigned short* __restrict__ qkv, unsigned short* __restrict__ att)
{
    __shared__ unsigned short Qs[64][QLD];
    __shared__ unsigned short Ks[KR][QLD];
    __shared__ unsigned short Vt[64][VLDP];
    __shared__ unsigned short Pws[4][16][VLDP];

    const int q0 = blockIdx.x * 64;
    const int bh = blockIdx.y;
    const int b = bh >> 3, h = bh & 7;
    const int t = threadIdx.x;
    const int wq = t >> 6, l = t & 63;
    const int quad = l >> 4, lo = l & 15;

    const size_t baseQ = (size_t)(b * T_) * QKV_LD + h * HD_;

    for (int c = t; c < 512; c += 256) {
        int row = c >> 3, cg = c & 7;
        *(short8*)(&Qs[row][cg * 8]) =
            *(const short8*)(&qkv[baseQ + (size_t)(q0 + row) * QKV_LD + cg * 8]);
    }
    for (int c = t; c < 768; c += 256) {
        int row = c >> 3, cg = c & 7;
        int g = q0 - WHALF_ + row;
        short8 kv = (short8)(short)0;
        if (g >= 0 && g < T_)
            kv = *(const short8*)(&qkv[baseQ + 512 + (size_t)g * QKV_LD + cg * 8]);
        *(short8*)(&Ks[row][cg * 8]) = kv;
    }
    for (int c = t; c < 768; c += 256) {
        int row = c >> 3, cg = c & 7;
        int g = q0 - WHALF_ + row;
        short8 vv = (short8)(short)0;
        if (g >= 0 && g < T_)
            vv = *(const short8*)(&qkv[baseQ + 1024 + (size_t)g * QKV_LD + cg * 8]);
        #pragma unroll
        for (int j = 0; j < 8; ++j) Vt[cg * 8 + j][row] = vv[j];
    }
    __syncthreads();

    floatx4 S[6];
    #pragma unroll
    for (int kt = 0; kt < 6; ++kt) S[kt] = (floatx4)0.0f;
    short8 aq[2];
    #pragma unroll
    for (int ks = 0; ks < 2; ++ks)
        aq[ks] = *(const short8*)(&Qs[wq * 16 + lo][ks * 32 + quad * 8]);
    #pragma unroll
    for (int kt = 0; kt < 6; ++kt) {
        #pragma unroll
        for (int ks = 0; ks < 2; ++ks) {
            short8 bk8 = *(const short8*)(&Ks[kt * 16 + lo][ks * 32 + quad * 8]);
            S[kt] = __builtin_amdgcn_mfma_f32_16x16x32_bf16(aq[ks], bk8, S[kt], 0, 0, 0);
        }
    }

    float inv_r[4];
    #pragma unroll
    for (int r = 0; r < 4; ++r) {
        int qi = q0 + wq * 16 + quad * 4 + r;
        float mx = -1e30f;
        float sv[6]; bool vd[6];
        #pragma unroll
        for (int kt = 0; kt < 6; ++kt) {
            int j = q0 - WHALF_ + kt * 16 + lo;
            bool ok = (j >= qi - WHALF_) && (j < qi + WHALF_) && (j >= 0) && (j < T_);
            float s = S[kt][r] * 0.125f;
            sv[kt] = s; vd[kt] = ok;
            mx = (ok && s > mx) ? s : mx;
        }
        #pragma unroll
        for (int mm = 1; mm < 16; mm <<= 1) mx = fmaxf(mx, __shfl_xor(mx, mm, 16));
        float den = 0.f;
        #pragma unroll
        for (int kt = 0; kt < 6; ++kt) {
            float e = vd[kt] ? __expf(sv[kt] - mx) : 0.f;
            Pws[wq][quad * 4 + r][kt * 16 + lo] = f2bf(e);
            den += e;
        }
        #pragma unroll
        for (int mm = 1; mm < 16; mm <<= 1) den += __shfl_xor(den, mm, 16);
        inv_r[r] = 1.0f / den;
    }
    __syncthreads();

    floatx4 O[4];
    #pragma unroll
    for (int nt = 0; nt < 4; ++nt) O[nt] = (floatx4)0.0f;
    #pragma unroll
    for (int ks = 0; ks < 3; ++ks) {
        short8 ap = *(const short8*)(&Pws[wq][lo][ks * 32 + quad * 8]);
        #pragma unroll
        for (int nt = 0; nt < 4; ++nt) {
            short8 bv8 = *(const short8*)(&Vt[nt * 16 + lo][ks * 32 + quad * 8]);
            O[nt] = __builtin_amdgcn_mfma_f32_16x16x32_bf16(ap, bv8, O[nt], 0, 0, 0);
        }
    }

    #pragma unroll
    for (int r = 0; r < 4; ++r) {
        int qi = q0 + wq * 16 + quad * 4 + r;
        size_t rowb = (size_t)(b * T_ + qi) * D_ + h * HD_;
        #pragma unroll
        for (int nt = 0; nt < 4; ++nt)
            att[rowb + nt * 16 + lo] = f2bf(O[nt][r] * inv_r[r]);
    }
}

// ---------------------------------------------------------------------------
extern "C" void kernel_launch(void* const* d_in, const int* in_sizes, int n_in,
                              void* d_out, int out_size, void* d_ws, size_t ws_size,
                              hipStream_t stream) {
    const float* x  = (const float*)d_in[0];
    const float* Wq = (const float*)d_in[1];
    const float* bq = (const float*)d_in[2];
    const float* Wk = (const float*)d_in[3];
    const float* bk = (const float*)d_in[4];
    const float* Wv = (const float*)d_in[5];
    const float* bv = (const float*)d_in[6];
    const float* Wo = (const float*)d_in[7];
    const float* bo = (const float*)d_in[8];
    float* out = (float*)d_out;

    char* ws = (char*)d_ws;
    unsigned short* xb   = (unsigned short*)(ws);                 //  4.00 MB
    unsigned short* wqkv = (unsigned short*)(ws +  4194304);      //  1.50 MB
    unsigned short* wob  = (unsigned short*)(ws +  5767168);      //  0.50 MB
    float*          bqkv = (float*)         (ws +  6291456);      //  6 KB
    unsigned short* qkvb = (unsigned short*)(ws +  6297600);      // 12.00 MB
    unsigned short* attb = (unsigned short*)(ws + 18880512);      //  4.00 MB

    cast_all<<<3073, 256, 0, stream>>>(x, Wq, Wk, Wv, Wo, bq, bk, bv,
                                       xb, wqkv, wob, bqkv);

    // fused QKV projection: 768 blocks = 3/CU
    gemm_qkv<<<dim3(Mtot / 128, QKV_LD / 64), 256, 0, stream>>>(
        xb, wqkv, bqkv, qkvb);

    // local attention (bf16 in/out)
    attn_mfma<<<dim3(T_ / 64, B_ * H_), 256, 0, stream>>>(qkvb, attb);

    // output projection: 512 blocks = 2/CU
    gemm_out<<<dim3(Mtot / 64, D_ / 64), 256, 0, stream>>>(attb, wob, bo, out);
}

// Round 7
// 106.766 us; speedup vs baseline: 1.3256x; 1.0169x over previous
//
#include <hip/hip_runtime.h>

#define B_  2
#define T_  2048
#define D_  512
#define H_  8
#define HD_ 64
#define WHALF_ 16
#define Mtot (B_*T_)
#define QKV_LD 1536

typedef __attribute__((ext_vector_type(8))) short short8;   // 8 bf16 in 4 VGPRs
typedef __attribute__((ext_vector_type(4))) float floatx4;  // MFMA accumulator

__device__ __forceinline__ unsigned short f2bf(float f) {
    unsigned u = __float_as_uint(f);
    u = (u + 0x7fffu + ((u >> 16) & 1u)) >> 16;   // RNE
    return (unsigned short)u;
}

__device__ __forceinline__ void glds16(const unsigned short* g, unsigned short* l) {
    // async global->LDS, 16 B/lane; LDS dest = wave-uniform base + lane*16
    __builtin_amdgcn_global_load_lds(
        (const __attribute__((address_space(1))) void*)g,
        (__attribute__((address_space(3))) void*)l, 16, 0, 0);
}

// ---------------------------------------------------------------------------
// One fused cast kernel: blocks 0..2047 cast x (fp32->bf16), 2048..3071 cast
// the 4 weight matrices into wqkv=[Wq;Wk;Wv] + wob, block 3072 packs bqkv.
// ---------------------------------------------------------------------------
__global__ __launch_bounds__(256) void cast_all(
    const float* __restrict__ x,
    const float* __restrict__ Wq, const float* __restrict__ Wk,
    const float* __restrict__ Wv, const float* __restrict__ Wo,
    const float* __restrict__ bq, const float* __restrict__ bk,
    const float* __restrict__ bv,
    unsigned short* __restrict__ xb,
    unsigned short* __restrict__ wqkv, unsigned short* __restrict__ wob,
    float* __restrict__ bqkv)
{
    if (blockIdx.x < 2048) {
        int i = blockIdx.x * 256 + threadIdx.x;
        float4 f = ((const float4*)x)[i];
        ushort4 o;
        o.x = f2bf(f.x); o.y = f2bf(f.y); o.z = f2bf(f.z); o.w = f2bf(f.w);
        ((ushort4*)xb)[i] = o;
    } else if (blockIdx.x < 3072) {
        int gid = (blockIdx.x - 2048) * 256 + threadIdx.x;
        int m   = gid >> 16;
        int idx = gid & 0xFFFF;
        const float* src = (m == 0) ? Wq : (m == 1) ? Wk : (m == 2) ? Wv : Wo;
        float4 f = ((const float4*)src)[idx];
        ushort4 o;
        o.x = f2bf(f.x); o.y = f2bf(f.y); o.z = f2bf(f.z); o.w = f2bf(f.w);
        if (m < 3) ((ushort4*)wqkv)[(m << 16) + idx] = o;
        else       ((ushort4*)wob)[idx] = o;
    } else {
        for (int i = threadIdx.x; i < 384; i += 256) {
            const float* src = (i < 128) ? bq : (i < 256) ? bk : bv;
            ((float4*)bqkv)[i] = ((const float4*)src)[i & 127];
        }
    }
}

// ---------------------------------------------------------------------------
// GEMM1: qkvb[4096,1536](bf16) = xb @ wqkv^T + bqkv.
// Tile 128x64, BK=64 (8 K-iters), glds(16B) staging into unpadded 128 B rows
// with XOR swizzle: physical colgrp cg holds logical colgrp cg^(row&7).
// Swizzle is applied on the GLOBAL address side (lane's LDS slot is fixed).
// Fragment b128 reads then span 8 distinct bank-quads -> 2-way only (free).
// 768 blocks = 3/CU.
// ---------------------------------------------------------------------------
__global__ __launch_bounds__(256) void gemm_qkv(
    const unsigned short* __restrict__ A, const unsigned short* __restrict__ W,
    const float* __restrict__ bias, unsigned short* __restrict__ C)
{
    __shared__ unsigned short As[128 * 64];   // 16 KB
    __shared__ unsigned short Bs[64 * 64];    //  8 KB

    const int t  = threadIdx.x;
    const int m0 = blockIdx.x * 128;
    const int n0 = blockIdx.y * 64;
    const int w  = t >> 6, l = t & 63;
    const int quad = l >> 4, lo = l & 15;
    const int wm = w & 1, wn = w >> 1;

    // staging: chunk = 8 rows x 128 B; lane l -> row l>>3, physical colgrp l&7,
    // which must receive logical colgrp (l&7)^(l>>3)  (row&7 == l>>3 here).
    const int lr = l >> 3;
    const int csw = ((l & 7) ^ lr) * 8;       // swizzled global col offset (elems)
    // A: 16 chunks, wave w stages rows [32w, 32w+32)
    const unsigned short* Ag[4];
    unsigned short* ldsA[4];
    #pragma unroll
    for (int p = 0; p < 4; ++p) {
        Ag[p] = A + (size_t)(m0 + 32 * w + 8 * p + lr) * 512 + csw;
        ldsA[p] = &As[(32 * w + 8 * p) * 64];
    }
    // B: 8 chunks, wave w stages rows [16w, 16w+16)
    const unsigned short* Bg[2];
    unsigned short* ldsB[2];
    #pragma unroll
    for (int p = 0; p < 2; ++p) {
        Bg[p] = W + (size_t)(n0 + 16 * w + 8 * p + lr) * 512 + csw;
        ldsB[p] = &Bs[(16 * w + 8 * p) * 64];
    }

    floatx4 acc[4][2];
    #pragma unroll
    for (int i = 0; i < 4; ++i) { acc[i][0] = (floatx4)0.0f; acc[i][1] = (floatx4)0.0f; }

    const int swlo = lo & 7;                  // row&7 for all fragment rows

    for (int k0 = 0; k0 < 512; k0 += 64) {
        #pragma unroll
        for (int p = 0; p < 4; ++p) glds16(Ag[p] + k0, ldsA[p]);
        #pragma unroll
        for (int p = 0; p < 2; ++p) glds16(Bg[p] + k0, ldsB[p]);
        __syncthreads();

        #pragma unroll
        for (int ks = 0; ks < 2; ++ks) {
            const int cg = ((ks * 4 + quad) ^ swlo) * 8;   // swizzled read offset
            short8 b0 = *(const short8*)(&Bs[(wn * 32 + lo) * 64 + cg]);
            short8 b1 = *(const short8*)(&Bs[(wn * 32 + 16 + lo) * 64 + cg]);
            #pragma unroll
            for (int i = 0; i < 4; ++i) {
                short8 a = *(const short8*)(&As[(wm * 64 + i * 16 + lo) * 64 + cg]);
                acc[i][0] = __builtin_amdgcn_mfma_f32_16x16x32_bf16(a, b0, acc[i][0], 0, 0, 0);
                acc[i][1] = __builtin_amdgcn_mfma_f32_16x16x32_bf16(a, b1, acc[i][1], 0, 0, 0);
            }
        }
        __syncthreads();
    }

    #pragma unroll
    for (int i = 0; i < 4; ++i) {
        int rbase = m0 + wm * 64 + i * 16 + quad * 4;
        #pragma unroll
        for (int j = 0; j < 2; ++j) {
            int col = n0 + wn * 32 + j * 16 + lo;
            float bv = bias[col];
            #pragma unroll
            for (int r = 0; r < 4; ++r)
                C[(size_t)(rbase + r) * QKV_LD + col] = f2bf(acc[i][j][r] + bv);
        }
    }
}

// ---------------------------------------------------------------------------
// GEMM2: out[4096,512](f32) = attb(bf16) @ wob^T + bo.
// Tile 64x64, BK=64 (8 K-iters), same swizzled glds staging. 512 blocks=2/CU.
// ---------------------------------------------------------------------------
__global__ __launch_bounds__(256) void gemm_out(
    const unsigned short* __restrict__ attb, const unsigned short* __restrict__ wob,
    const float* __restrict__ bo, float* __restrict__ out)
{
    __shared__ unsigned short As[64 * 64];
    __shared__ unsigned short Bs[64 * 64];

    const int t  = threadIdx.x;
    const int m0 = blockIdx.x * 64;
    const int n0 = blockIdx.y * 64;
    const int w  = t >> 6, l = t & 63;
    const int quad = l >> 4, lo = l & 15;

    const int lr = l >> 3;
    const int csw = ((l & 7) ^ lr) * 8;
    const unsigned short* Ag[2]; unsigned short* ldsA[2];
    const unsigned short* Bg[2]; unsigned short* ldsB[2];
    #pragma unroll
    for (int p = 0; p < 2; ++p) {
        Ag[p] = attb + (size_t)(m0 + 16 * w + 8 * p + lr) * 512 + csw;
        ldsA[p] = &As[(16 * w + 8 * p) * 64];
        Bg[p] = wob + (size_t)(n0 + 16 * w + 8 * p + lr) * 512 + csw;
        ldsB[p] = &Bs[(16 * w + 8 * p) * 64];
    }

    floatx4 acc[4];
    #pragma unroll
    for (int j = 0; j < 4; ++j) acc[j] = (floatx4)0.0f;

    const int swlo = lo & 7;

    for (int k0 = 0; k0 < 512; k0 += 64) {
        #pragma unroll
        for (int p = 0; p < 2; ++p) { glds16(Ag[p] + k0, ldsA[p]); glds16(Bg[p] + k0, ldsB[p]); }
        __syncthreads();

        #pragma unroll
        for (int ks = 0; ks < 2; ++ks) {
            const int cg = ((ks * 4 + quad) ^ swlo) * 8;
            short8 a = *(const short8*)(&As[(w * 16 + lo) * 64 + cg]);
            #pragma unroll
            for (int j = 0; j < 4; ++j) {
                short8 b = *(const short8*)(&Bs[(j * 16 + lo) * 64 + cg]);
                acc[j] = __builtin_amdgcn_mfma_f32_16x16x32_bf16(a, b, acc[j], 0, 0, 0);
            }
        }
        __syncthreads();
    }

    #pragma unroll
    for (int j = 0; j < 4; ++j) {
        int col = n0 + j * 16 + lo;
        float bv = bo[col];
        #pragma unroll
        for (int r = 0; r < 4; ++r) {
            int row = m0 + w * 16 + quad * 4 + r;
            out[(size_t)row * 512 + col] = acc[j][r] + bv;
        }
    }
}

// ---------------------------------------------------------------------------
// MFMA local-window attention (unchanged — correct).
// ---------------------------------------------------------------------------
#define KR 96
#define QLD 72
#define VLDP 104

__global__ __launch_bounds__(256) void attn_mfma(
    const unsigned short* __restrict__ qkv, unsigned short* __restrict__ att)
{
    __shared__ unsigned short Qs[64][QLD];
    __shared__ unsigned short Ks[KR][QLD];
    __shared__ unsigned short Vt[64][VLDP];
    __shared__ unsigned short Pws[4][16][VLDP];

    const int q0 = blockIdx.x * 64;
    const int bh = blockIdx.y;
    const int b = bh >> 3, h = bh & 7;
    const int t = threadIdx.x;
    const int wq = t >> 6, l = t & 63;
    const int quad = l >> 4, lo = l & 15;

    const size_t baseQ = (size_t)(b * T_) * QKV_LD + h * HD_;

    for (int c = t; c < 512; c += 256) {
        int row = c >> 3, cg = c & 7;
        *(short8*)(&Qs[row][cg * 8]) =
            *(const short8*)(&qkv[baseQ + (size_t)(q0 + row) * QKV_LD + cg * 8]);
    }
    for (int c = t; c < 768; c += 256) {
        int row = c >> 3, cg = c & 7;
        int g = q0 - WHALF_ + row;
        short8 kv = (short8)(short)0;
        if (g >= 0 && g < T_)
            kv = *(const short8*)(&qkv[baseQ + 512 + (size_t)g * QKV_LD + cg * 8]);
        *(short8*)(&Ks[row][cg * 8]) = kv;
    }
    for (int c = t; c < 768; c += 256) {
        int row = c >> 3, cg = c & 7;
        int g = q0 - WHALF_ + row;
        short8 vv = (short8)(short)0;
        if (g >= 0 && g < T_)
            vv = *(const short8*)(&qkv[baseQ + 1024 + (size_t)g * QKV_LD + cg * 8]);
        #pragma unroll
        for (int j = 0; j < 8; ++j) Vt[cg * 8 + j][row] = vv[j];
    }
    __syncthreads();

    floatx4 S[6];
    #pragma unroll
    for (int kt = 0; kt < 6; ++kt) S[kt] = (floatx4)0.0f;
    short8 aq[2];
    #pragma unroll
    for (int ks = 0; ks < 2; ++ks)
        aq[ks] = *(const short8*)(&Qs[wq * 16 + lo][ks * 32 + quad * 8]);
    #pragma unroll
    for (int kt = 0; kt < 6; ++kt) {
        #pragma unroll
        for (int ks = 0; ks < 2; ++ks) {
            short8 bk8 = *(const short8*)(&Ks[kt * 16 + lo][ks * 32 + quad * 8]);
            S[kt] = __builtin_amdgcn_mfma_f32_16x16x32_bf16(aq[ks], bk8, S[kt], 0, 0, 0);
        }
    }

    float inv_r[4];
    #pragma unroll
    for (int r = 0; r < 4; ++r) {
        int qi = q0 + wq * 16 + quad * 4 + r;
        float mx = -1e30f;
        float sv[6]; bool vd[6];
        #pragma unroll
        for (int kt = 0; kt < 6; ++kt) {
            int j = q0 - WHALF_ + kt * 16 + lo;
            bool ok = (j >= qi - WHALF_) && (j < qi + WHALF_) && (j >= 0) && (j < T_);
            float s = S[kt][r] * 0.125f;
            sv[kt] = s; vd[kt] = ok;
            mx = (ok && s > mx) ? s : mx;
        }
        #pragma unroll
        for (int mm = 1; mm < 16; mm <<= 1) mx = fmaxf(mx, __shfl_xor(mx, mm, 16));
        float den = 0.f;
        #pragma unroll
        for (int kt = 0; kt < 6; ++kt) {
            float e = vd[kt] ? __expf(sv[kt] - mx) : 0.f;
            Pws[wq][quad * 4 + r][kt * 16 + lo] = f2bf(e);
            den += e;
        }
        #pragma unroll
        for (int mm = 1; mm < 16; mm <<= 1) den += __shfl_xor(den, mm, 16);
        inv_r[r] = 1.0f / den;
    }
    __syncthreads();

    floatx4 O[4];
    #pragma unroll
    for (int nt = 0; nt < 4; ++nt) O[nt] = (floatx4)0.0f;
    #pragma unroll
    for (int ks = 0; ks < 3; ++ks) {
        short8 ap = *(const short8*)(&Pws[wq][lo][ks * 32 + quad * 8]);
        #pragma unroll
        for (int nt = 0; nt < 4; ++nt) {
            short8 bv8 = *(const short8*)(&Vt[nt * 16 + lo][ks * 32 + quad * 8]);
            O[nt] = __builtin_amdgcn_mfma_f32_16x16x32_bf16(ap, bv8, O[nt], 0, 0, 0);
        }
    }

    #pragma unroll
    for (int r = 0; r < 4; ++r) {
        int qi = q0 + wq * 16 + quad * 4 + r;
        size_t rowb = (size_t)(b * T_ + qi) * D_ + h * HD_;
        #pragma unroll
        for (int nt = 0; nt < 4; ++nt)
            att[rowb + nt * 16 + lo] = f2bf(O[nt][r] * inv_r[r]);
    }
}

// ---------------------------------------------------------------------------
extern "C" void kernel_launch(void* const* d_in, const int* in_sizes, int n_in,
                              void* d_out, int out_size, void* d_ws, size_t ws_size,
                              hipStream_t stream) {
    const float* x  = (const float*)d_in[0];
    const float* Wq = (const float*)d_in[1];
    const float* bq = (const float*)d_in[2];
    const float* Wk = (const float*)d_in[3];
    const float* bk = (const float*)d_in[4];
    const float* Wv = (const float*)d_in[5];
    const float* bv = (const float*)d_in[6];
    const float* Wo = (const float*)d_in[7];
    const float* bo = (const float*)d_in[8];
    float* out = (float*)d_out;

    char* ws = (char*)d_ws;
    unsigned short* xb   = (unsigned short*)(ws);                 //  4.00 MB
    unsigned short* wqkv = (unsigned short*)(ws +  4194304);      //  1.50 MB
    unsigned short* wob  = (unsigned short*)(ws +  5767168);      //  0.50 MB
    float*          bqkv = (float*)         (ws +  6291456);      //  6 KB
    unsigned short* qkvb = (unsigned short*)(ws +  6297600);      // 12.00 MB
    unsigned short* attb = (unsigned short*)(ws + 18880512);      //  4.00 MB

    cast_all<<<3073, 256, 0, stream>>>(x, Wq, Wk, Wv, Wo, bq, bk, bv,
                                       xb, wqkv, wob, bqkv);

    // fused QKV projection: 768 blocks = 3/CU, BK=64, swizzled staging
    gemm_qkv<<<dim3(Mtot / 128, QKV_LD / 64), 256, 0, stream>>>(
        xb, wqkv, bqkv, qkvb);

    // local attention (bf16 in/out)
    attn_mfma<<<dim3(T_ / 64, B_ * H_), 256, 0, stream>>>(qkvb, attb);

    // output projection: 512 blocks = 2/CU, BK=64, swizzled staging
    gemm_out<<<dim3(Mtot / 64, D_ / 64), 256, 0, stream>>>(attb, wob, bo, out);
}

// Round 8
// 105.684 us; speedup vs baseline: 1.3391x; 1.0102x over previous
//
#include <hip/hip_runtime.h>

#define B_  2
#define T_  2048
#define D_  512
#define H_  8
#define HD_ 64
#define WHALF_ 16
#define Mtot (B_*T_)
#define QKV_LD 1536

typedef __attribute__((ext_vector_type(8))) short short8;   // 8 bf16 in 4 VGPRs
typedef __attribute__((ext_vector_type(4))) short short4v;
typedef __attribute__((ext_vector_type(4))) float floatx4;  // MFMA accumulator

__device__ __forceinline__ unsigned short f2bf(float f) {
    unsigned u = __float_as_uint(f);
    u = (u + 0x7fffu + ((u >> 16) & 1u)) >> 16;   // RNE
    return (unsigned short)u;
}

__device__ __forceinline__ void glds16(const unsigned short* g, unsigned short* l) {
    // async global->LDS, 16 B/lane; LDS dest = wave-uniform base + lane*16
    __builtin_amdgcn_global_load_lds(
        (const __attribute__((address_space(1))) void*)g,
        (__attribute__((address_space(3))) void*)l, 16, 0, 0);
}

// ---------------------------------------------------------------------------
// Fused cast kernel (unchanged).
// ---------------------------------------------------------------------------
__global__ __launch_bounds__(256) void cast_all(
    const float* __restrict__ x,
    const float* __restrict__ Wq, const float* __restrict__ Wk,
    const float* __restrict__ Wv, const float* __restrict__ Wo,
    const float* __restrict__ bq, const float* __restrict__ bk,
    const float* __restrict__ bv,
    unsigned short* __restrict__ xb,
    unsigned short* __restrict__ wqkv, unsigned short* __restrict__ wob,
    float* __restrict__ bqkv)
{
    if (blockIdx.x < 2048) {
        int i = blockIdx.x * 256 + threadIdx.x;
        float4 f = ((const float4*)x)[i];
        ushort4 o;
        o.x = f2bf(f.x); o.y = f2bf(f.y); o.z = f2bf(f.z); o.w = f2bf(f.w);
        ((ushort4*)xb)[i] = o;
    } else if (blockIdx.x < 3072) {
        int gid = (blockIdx.x - 2048) * 256 + threadIdx.x;
        int m   = gid >> 16;
        int idx = gid & 0xFFFF;
        const float* src = (m == 0) ? Wq : (m == 1) ? Wk : (m == 2) ? Wv : Wo;
        float4 f = ((const float4*)src)[idx];
        ushort4 o;
        o.x = f2bf(f.x); o.y = f2bf(f.y); o.z = f2bf(f.z); o.w = f2bf(f.w);
        if (m < 3) ((ushort4*)wqkv)[(m << 16) + idx] = o;
        else       ((ushort4*)wob)[idx] = o;
    } else {
        for (int i = threadIdx.x; i < 384; i += 256) {
            const float* src = (i < 128) ? bq : (i < 256) ? bk : bv;
            ((float4*)bqkv)[i] = ((const float4*)src)[i & 127];
        }
    }
}

// ---------------------------------------------------------------------------
// GEMM1: qkvb[4096,1536](bf16) = xb @ wqkv^T + bqkv.
// Tile 64x64, BK=64, swizzled glds staging. 1536 blocks = 6/CU (latency
// hiding via co-residency; LDS 16 KB, VGPR ~64 permit it).
// ---------------------------------------------------------------------------
__global__ __launch_bounds__(256) void gemm_qkv(
    const unsigned short* __restrict__ A, const unsigned short* __restrict__ W,
    const float* __restrict__ bias, unsigned short* __restrict__ C)
{
    __shared__ unsigned short As[64 * 64];
    __shared__ unsigned short Bs[64 * 64];

    const int t  = threadIdx.x;
    const int m0 = blockIdx.x * 64;
    const int n0 = blockIdx.y * 64;          // global col in [0,1536)
    const int w  = t >> 6, l = t & 63;
    const int quad = l >> 4, lo = l & 15;

    const int lr = l >> 3;
    const int csw = ((l & 7) ^ lr) * 8;      // swizzled global col offset
    const unsigned short* Ag[2]; unsigned short* ldsA[2];
    const unsigned short* Bg[2]; unsigned short* ldsB[2];
    #pragma unroll
    for (int p = 0; p < 2; ++p) {
        Ag[p] = A + (size_t)(m0 + 16 * w + 8 * p + lr) * 512 + csw;
        ldsA[p] = &As[(16 * w + 8 * p) * 64];
        Bg[p] = W + (size_t)(n0 + 16 * w + 8 * p + lr) * 512 + csw;
        ldsB[p] = &Bs[(16 * w + 8 * p) * 64];
    }

    floatx4 acc[4];
    #pragma unroll
    for (int j = 0; j < 4; ++j) acc[j] = (floatx4)0.0f;

    const int swlo = lo & 7;

    for (int k0 = 0; k0 < 512; k0 += 64) {
        #pragma unroll
        for (int p = 0; p < 2; ++p) { glds16(Ag[p] + k0, ldsA[p]); glds16(Bg[p] + k0, ldsB[p]); }
        __syncthreads();

        #pragma unroll
        for (int ks = 0; ks < 2; ++ks) {
            const int cg = ((ks * 4 + quad) ^ swlo) * 8;
            short8 a = *(const short8*)(&As[(w * 16 + lo) * 64 + cg]);
            #pragma unroll
            for (int j = 0; j < 4; ++j) {
                short8 b = *(const short8*)(&Bs[(j * 16 + lo) * 64 + cg]);
                acc[j] = __builtin_amdgcn_mfma_f32_16x16x32_bf16(a, b, acc[j], 0, 0, 0);
            }
        }
        __syncthreads();
    }

    #pragma unroll
    for (int j = 0; j < 4; ++j) {
        int col = n0 + j * 16 + lo;
        float bv = bias[col];
        #pragma unroll
        for (int r = 0; r < 4; ++r) {
            int row = m0 + w * 16 + quad * 4 + r;
            C[(size_t)row * QKV_LD + col] = f2bf(acc[j][r] + bv);
        }
    }
}

// ---------------------------------------------------------------------------
// GEMM2: out[4096,512](f32) = attb(bf16) @ wob^T + bo. (unchanged from R7)
// ---------------------------------------------------------------------------
__global__ __launch_bounds__(256) void gemm_out(
    const unsigned short* __restrict__ attb, const unsigned short* __restrict__ wob,
    const float* __restrict__ bo, float* __restrict__ out)
{
    __shared__ unsigned short As[64 * 64];
    __shared__ unsigned short Bs[64 * 64];

    const int t  = threadIdx.x;
    const int m0 = blockIdx.x * 64;
    const int n0 = blockIdx.y * 64;
    const int w  = t >> 6, l = t & 63;
    const int quad = l >> 4, lo = l & 15;

    const int lr = l >> 3;
    const int csw = ((l & 7) ^ lr) * 8;
    const unsigned short* Ag[2]; unsigned short* ldsA[2];
    const unsigned short* Bg[2]; unsigned short* ldsB[2];
    #pragma unroll
    for (int p = 0; p < 2; ++p) {
        Ag[p] = attb + (size_t)(m0 + 16 * w + 8 * p + lr) * 512 + csw;
        ldsA[p] = &As[(16 * w + 8 * p) * 64];
        Bg[p] = wob + (size_t)(n0 + 16 * w + 8 * p + lr) * 512 + csw;
        ldsB[p] = &Bs[(16 * w + 8 * p) * 64];
    }

    floatx4 acc[4];
    #pragma unroll
    for (int j = 0; j < 4; ++j) acc[j] = (floatx4)0.0f;

    const int swlo = lo & 7;

    for (int k0 = 0; k0 < 512; k0 += 64) {
        #pragma unroll
        for (int p = 0; p < 2; ++p) { glds16(Ag[p] + k0, ldsA[p]); glds16(Bg[p] + k0, ldsB[p]); }
        __syncthreads();

        #pragma unroll
        for (int ks = 0; ks < 2; ++ks) {
            const int cg = ((ks * 4 + quad) ^ swlo) * 8;
            short8 a = *(const short8*)(&As[(w * 16 + lo) * 64 + cg]);
            #pragma unroll
            for (int j = 0; j < 4; ++j) {
                short8 b = *(const short8*)(&Bs[(j * 16 + lo) * 64 + cg]);
                acc[j] = __builtin_amdgcn_mfma_f32_16x16x32_bf16(a, b, acc[j], 0, 0, 0);
            }
        }
        __syncthreads();
    }

    #pragma unroll
    for (int j = 0; j < 4; ++j) {
        int col = n0 + j * 16 + lo;
        float bv = bo[col];
        #pragma unroll
        for (int r = 0; r < 4; ++r) {
            int row = m0 + w * 16 + quad * 4 + r;
            out[(size_t)row * 512 + col] = acc[j][r] + bv;
        }
    }
}

// ---------------------------------------------------------------------------
// MFMA local-window attention, band-restricted.
// Per 16-query tile wq, the 32-wide window only touches key chunk ks0=wq>>1
// and ks0+1 (keys [32*ks0, 32*ks0+64) of the 96 staged). So: QK^T over 4
// 16-key tiles (8 MFMA), PV over 2 32-key chunks (8 MFMA). V staged
// row-major stride 76 (quad bank-step 16 -> 2-way = free) and B-frags
// gathered via scalar b16 reads — no transposed staging, no 8-way conflicts.
// Pws is wave-private -> no barrier between softmax and PV.
// ---------------------------------------------------------------------------
#define QLD 72
#define VLD 76

__global__ __launch_bounds__(256) void attn_mfma(
    const unsigned short* __restrict__ qkv, unsigned short* __restrict__ att)
{
    __shared__ unsigned short Qs[64][QLD];
    __shared__ unsigned short Ks[96][QLD];
    __shared__ unsigned short Vs[96][VLD];
    __shared__ unsigned short Pws[4][16][QLD];   // cols relative to 32*ks0, 64 used

    const int q0 = blockIdx.x * 64;
    const int bh = blockIdx.y;
    const int b = bh >> 3, h = bh & 7;
    const int t = threadIdx.x;
    const int wq = t >> 6, l = t & 63;
    const int quad = l >> 4, lo = l & 15;

    const size_t baseQ = (size_t)(b * T_) * QKV_LD + h * HD_;

    for (int c = t; c < 512; c += 256) {          // Q: 64 rows
        int row = c >> 3, cg = c & 7;
        *(short8*)(&Qs[row][cg * 8]) =
            *(const short8*)(&qkv[baseQ + (size_t)(q0 + row) * QKV_LD + cg * 8]);
    }
    for (int c = t; c < 768; c += 256) {          // K: 96 rows
        int row = c >> 3, cg = c & 7;
        int g = q0 - WHALF_ + row;
        short8 kv = (short8)(short)0;
        if (g >= 0 && g < T_)
            kv = *(const short8*)(&qkv[baseQ + 512 + (size_t)g * QKV_LD + cg * 8]);
        *(short8*)(&Ks[row][cg * 8]) = kv;
    }
    for (int c = t; c < 768; c += 256) {          // V: 96 rows, row-major
        int row = c >> 3, cg = c & 7;
        int g = q0 - WHALF_ + row;
        short8 vv = (short8)(short)0;
        if (g >= 0 && g < T_)
            vv = *(const short8*)(&qkv[baseQ + 1024 + (size_t)g * QKV_LD + cg * 8]);
        // row stride 76 is not 8-aligned for b128; two 8 B writes (aligned)
        short4v lo4 = { vv[0], vv[1], vv[2], vv[3] };
        short4v hi4 = { vv[4], vv[5], vv[6], vv[7] };
        *(short4v*)(&Vs[row][cg * 8])     = lo4;
        *(short4v*)(&Vs[row][cg * 8 + 4]) = hi4;
    }
    __syncthreads();

    const int ks0 = wq >> 1;                      // first 32-key chunk
    const int kb  = ks0 * 2;                      // first 16-key tile

    // ---- S = Q K^T over 4 key tiles ----
    floatx4 S[4];
    #pragma unroll
    for (int tt = 0; tt < 4; ++tt) S[tt] = (floatx4)0.0f;
    short8 aq[2];
    #pragma unroll
    for (int ks = 0; ks < 2; ++ks)
        aq[ks] = *(const short8*)(&Qs[wq * 16 + lo][ks * 32 + quad * 8]);
    #pragma unroll
    for (int tt = 0; tt < 4; ++tt) {
        #pragma unroll
        for (int ks = 0; ks < 2; ++ks) {
            short8 bk8 = *(const short8*)(&Ks[(kb + tt) * 16 + lo][ks * 32 + quad * 8]);
            S[tt] = __builtin_amdgcn_mfma_f32_16x16x32_bf16(aq[ks], bk8, S[tt], 0, 0, 0);
        }
    }

    // ---- masked softmax; C-layout row=quad*4+r, col(key tile)=kb+tt ----
    float inv_r[4];
    #pragma unroll
    for (int r = 0; r < 4; ++r) {
        int qi = q0 + wq * 16 + quad * 4 + r;
        float mx = -1e30f;
        float sv[4]; bool vd[4];
        #pragma unroll
        for (int tt = 0; tt < 4; ++tt) {
            int j = q0 - WHALF_ + (kb + tt) * 16 + lo;
            bool ok = (j >= qi - WHALF_) && (j < qi + WHALF_) && (j >= 0) && (j < T_);
            float s = S[tt][r] * 0.125f;
            sv[tt] = s; vd[tt] = ok;
            mx = (ok && s > mx) ? s : mx;
        }
        #pragma unroll
        for (int mm = 1; mm < 16; mm <<= 1) mx = fmaxf(mx, __shfl_xor(mx, mm, 16));
        float den = 0.f;
        #pragma unroll
        for (int tt = 0; tt < 4; ++tt) {
            float e = vd[tt] ? __expf(sv[tt] - mx) : 0.f;
            Pws[wq][quad * 4 + r][tt * 16 + lo] = f2bf(e);
            den += e;
        }
        #pragma unroll
        for (int mm = 1; mm < 16; mm <<= 1) den += __shfl_xor(den, mm, 16);
        inv_r[r] = 1.0f / den;
    }
    // Pws is wave-private: in-wave lgkmcnt ordering suffices, no barrier.

    // ---- O = P V over 2 key chunks; B-frags gathered from row-major Vs ----
    floatx4 O[4];
    #pragma unroll
    for (int nt = 0; nt < 4; ++nt) O[nt] = (floatx4)0.0f;
    #pragma unroll
    for (int ksr = 0; ksr < 2; ++ksr) {
        short8 ap = *(const short8*)(&Pws[wq][lo][ksr * 32 + quad * 8]);
        const int krow = (ks0 + ksr) * 32 + quad * 8;
        #pragma unroll
        for (int nt = 0; nt < 4; ++nt) {
            short8 bv8;
            #pragma unroll
            for (int j = 0; j < 8; ++j)
                bv8[j] = (short)Vs[krow + j][nt * 16 + lo];
            O[nt] = __builtin_amdgcn_mfma_f32_16x16x32_bf16(ap, bv8, O[nt], 0, 0, 0);
        }
    }

    // ---- epilogue: scale by 1/den, bf16 out ----
    #pragma unroll
    for (int r = 0; r < 4; ++r) {
        int qi = q0 + wq * 16 + quad * 4 + r;
        size_t rowb = (size_t)(b * T_ + qi) * D_ + h * HD_;
        #pragma unroll
        for (int nt = 0; nt < 4; ++nt)
            att[rowb + nt * 16 + lo] = f2bf(O[nt][r] * inv_r[r]);
    }
}

// ---------------------------------------------------------------------------
extern "C" void kernel_launch(void* const* d_in, const int* in_sizes, int n_in,
                              void* d_out, int out_size, void* d_ws, size_t ws_size,
                              hipStream_t stream) {
    const float* x  = (const float*)d_in[0];
    const float* Wq = (const float*)d_in[1];
    const float* bq = (const float*)d_in[2];
    const float* Wk = (const float*)d_in[3];
    const float* bk = (const float*)d_in[4];
    const float* Wv = (const float*)d_in[5];
    const float* bv = (const float*)d_in[6];
    const float* Wo = (const float*)d_in[7];
    const float* bo = (const float*)d_in[8];
    float* out = (float*)d_out;

    char* ws = (char*)d_ws;
    unsigned short* xb   = (unsigned short*)(ws);                 //  4.00 MB
    unsigned short* wqkv = (unsigned short*)(ws +  4194304);      //  1.50 MB
    unsigned short* wob  = (unsigned short*)(ws +  5767168);      //  0.50 MB
    float*          bqkv = (float*)         (ws +  6291456);      //  6 KB
    unsigned short* qkvb = (unsigned short*)(ws +  6297600);      // 12.00 MB
    unsigned short* attb = (unsigned short*)(ws + 18880512);      //  4.00 MB

    cast_all<<<3073, 256, 0, stream>>>(x, Wq, Wk, Wv, Wo, bq, bk, bv,
                                       xb, wqkv, wob, bqkv);

    // fused QKV projection: 1536 blocks = 6/CU
    gemm_qkv<<<dim3(Mtot / 64, QKV_LD / 64), 256, 0, stream>>>(
        xb, wqkv, bqkv, qkvb);

    // local attention (band-restricted MFMA)
    attn_mfma<<<dim3(T_ / 64, B_ * H_), 256, 0, stream>>>(qkvb, attb);

    // output projection: 512 blocks = 2/CU
    gemm_out<<<dim3(Mtot / 64, D_ / 64), 256, 0, stream>>>(attb, wob, bo, out);
}